// Round 1
// baseline (514.969 us; speedup 1.0000x reference)
//
#include <hip/hip_runtime.h>
#include <hip/hip_bf16.h>

// ---------------------------------------------------------------------------
// GAT (2 layers) + mean pool + MLP head, fp32.
// Pipeline:
//  1) gemm_f32:  h1pre = x @ W1                       [N,512]
//  2) al1:       al_s1/al_d1 per (node,head)          [N,4]
//  3) CSR build by dst: count -> scan -> scatter (int atomics only)
//  4) edgew1:    w = exp(leaky(al_s[src]+al_d[dst]))  [Et,4]
//  5) denom1:    per (node,head) CSR sum of w         [N,4]
//  6) agg1:      out1 = elu(sum alpha*h1pre[src]+b1)  [N,512]
//  7) gemm_f32:  h2pre = out1 @ W2                    [N,64]   (aliases h1pre)
//  8) al2 / edgew2 / denom2 / agg2 -> out2 = elu(...) [N,64]   (aliases out1)
//  9) pool: per-graph mean via binary search on sorted batch
// 10) fc: 64->32 relu -> 1 sigmoid
// ---------------------------------------------------------------------------

#define LRELU(v) ((v) > 0.0f ? (v) : 0.2f * (v))
#define ELU(v)   ((v) > 0.0f ? (v) : expm1f(v))

// ---------------- generic fp32 GEMM: C[M,N] = A[M,K] @ B[K,N] --------------
// 64x64 tile, BK=16, 256 threads, 4x4 microtile. N%64==0, K%16==0 assumed.
__global__ __launch_bounds__(256) void gemm_f32(const float* __restrict__ A,
                                                const float* __restrict__ B,
                                                float* __restrict__ C,
                                                int M, int N, int K) {
    __shared__ float As[16][64];
    __shared__ float Bs[16][64];
    int tid = threadIdx.x;
    int row0 = blockIdx.x * 64, col0 = blockIdx.y * 64;
    int tx = tid & 15, ty = tid >> 4;

    int la_r = tid >> 2;          // 0..63
    int la_k = (tid & 3) * 4;     // 0,4,8,12
    int lb_k = tid >> 4;          // 0..15
    int lb_c = (tid & 15) * 4;    // 0..60

    float acc[4][4] = {};

    for (int k0 = 0; k0 < K; k0 += 16) {
        int ar = row0 + la_r;
        float4 av = make_float4(0.f, 0.f, 0.f, 0.f);
        if (ar < M) av = *(const float4*)(A + (size_t)ar * K + k0 + la_k);
        As[la_k + 0][la_r] = av.x;
        As[la_k + 1][la_r] = av.y;
        As[la_k + 2][la_r] = av.z;
        As[la_k + 3][la_r] = av.w;
        float4 bv = *(const float4*)(B + (size_t)(k0 + lb_k) * N + col0 + lb_c);
        *(float4*)(&Bs[lb_k][lb_c]) = bv;
        __syncthreads();
#pragma unroll
        for (int kk = 0; kk < 16; ++kk) {
            float a[4], b[4];
#pragma unroll
            for (int i = 0; i < 4; ++i) a[i] = As[kk][ty * 4 + i];
#pragma unroll
            for (int j = 0; j < 4; ++j) b[j] = Bs[kk][tx * 4 + j];
#pragma unroll
            for (int i = 0; i < 4; ++i)
#pragma unroll
                for (int j = 0; j < 4; ++j) acc[i][j] += a[i] * b[j];
        }
        __syncthreads();
    }
#pragma unroll
    for (int i = 0; i < 4; ++i) {
        int r = row0 + ty * 4 + i;
        if (r < M) {
            float4 v = make_float4(acc[i][0], acc[i][1], acc[i][2], acc[i][3]);
            *(float4*)(C + (size_t)r * N + col0 + tx * 4) = v;
        }
    }
}

// ---------------- attention logits per node, layer 1 (H=4, O=128) ----------
__global__ __launch_bounds__(256) void al1_kernel(const float* __restrict__ h1pre,
                                                  const float* __restrict__ a_s,
                                                  const float* __restrict__ a_d,
                                                  float* __restrict__ alS,
                                                  float* __restrict__ alD, int Nn) {
    int n = blockIdx.x;
    int h = threadIdx.x >> 6, lane = threadIdx.x & 63;
    const float* row = h1pre + (size_t)n * 512 + h * 128;
    const float* as = a_s + h * 128;
    const float* ad = a_d + h * 128;
    float v0 = row[lane], v1 = row[lane + 64];
    float s = v0 * as[lane] + v1 * as[lane + 64];
    float d = v0 * ad[lane] + v1 * ad[lane + 64];
#pragma unroll
    for (int off = 32; off; off >>= 1) {
        s += __shfl_down(s, off);
        d += __shfl_down(d, off);
    }
    if (lane == 0) { alS[n * 4 + h] = s; alD[n * 4 + h] = d; }
}

// ---------------- CSR build ------------------------------------------------
__global__ __launch_bounds__(256) void count_kernel(const int* __restrict__ dst,
                                                    int E, int Nn, int* __restrict__ deg) {
    int e = blockIdx.x * 256 + threadIdx.x;
    if (e >= E + Nn) return;
    int d = (e < E) ? dst[e] : (e - E);
    atomicAdd(&deg[d], 1);
}

__global__ __launch_bounds__(1024) void scan_kernel(const int* __restrict__ deg,
                                                    int* __restrict__ offs, int n) {
    __shared__ int sh[1024];
    int tid = threadIdx.x;
    int carry = 0;
    if (tid == 0) offs[0] = 0;
    for (int base = 0; base < n; base += 1024) {
        int i = base + tid;
        int v = (i < n) ? deg[i] : 0;
        sh[tid] = v;
        __syncthreads();
        for (int off = 1; off < 1024; off <<= 1) {
            int t = (tid >= off) ? sh[tid - off] : 0;
            __syncthreads();
            sh[tid] += t;
            __syncthreads();
        }
        if (i < n) offs[i + 1] = carry + sh[tid];
        int total = sh[1023];
        __syncthreads();
        carry += total;
    }
}

__global__ __launch_bounds__(256) void scatter_kernel(const int* __restrict__ dst,
                                                      int E, int Nn,
                                                      const int* __restrict__ offs,
                                                      int* __restrict__ fill,
                                                      int* __restrict__ perm) {
    int e = blockIdx.x * 256 + threadIdx.x;
    if (e >= E + Nn) return;
    int d = (e < E) ? dst[e] : (e - E);
    int pos = offs[d] + atomicAdd(&fill[d], 1);
    perm[pos] = e;
}

// ---------------- per-edge exp(leaky(.)) weights ---------------------------
__global__ __launch_bounds__(256) void edgew1_kernel(const int* __restrict__ src,
                                                     const int* __restrict__ dst,
                                                     int E, int Nn,
                                                     const float* __restrict__ alS,
                                                     const float* __restrict__ alD,
                                                     float* __restrict__ wE) {
    int e = blockIdx.x * 256 + threadIdx.x;
    if (e >= E + Nn) return;
    int s = (e < E) ? src[e] : (e - E);
    int d = (e < E) ? dst[e] : (e - E);
    float4 as = *(const float4*)(alS + (size_t)s * 4);
    float4 ad = *(const float4*)(alD + (size_t)d * 4);
    float4 w;
    float t;
    t = as.x + ad.x; w.x = expf(LRELU(t));
    t = as.y + ad.y; w.y = expf(LRELU(t));
    t = as.z + ad.z; w.z = expf(LRELU(t));
    t = as.w + ad.w; w.w = expf(LRELU(t));
    *(float4*)(wE + (size_t)e * 4) = w;
}

__global__ __launch_bounds__(256) void denom1_kernel(const int* __restrict__ offs,
                                                     const int* __restrict__ perm,
                                                     const float* __restrict__ wE,
                                                     float* __restrict__ denom, int Nn) {
    int idx = blockIdx.x * 256 + threadIdx.x;
    if (idx >= Nn * 4) return;
    int n = idx >> 2, h = idx & 3;
    int s0 = offs[n], s1 = offs[n + 1];
    float sum = 0.f;
    for (int i = s0; i < s1; ++i) sum += wE[(size_t)perm[i] * 4 + h];
    denom[idx] = sum;
}

// ---------------- layer-1 aggregate: out1 = elu(sum alpha*h[src] + b1) -----
__global__ __launch_bounds__(256) void agg1_kernel(const float* __restrict__ h1pre,
                                                   const int* __restrict__ src,
                                                   const int* __restrict__ offs,
                                                   const int* __restrict__ perm,
                                                   const float* __restrict__ wE,
                                                   const float* __restrict__ denom,
                                                   const float* __restrict__ b1,
                                                   float* __restrict__ out1,
                                                   int E, int Nn) {
    int n = blockIdx.x;
    int t = threadIdx.x;
    int f = t * 2;
    int head = f >> 7;
    float dinv = 1.0f / denom[n * 4 + head];
    float ax = 0.f, ay = 0.f;
    int s0 = offs[n], s1 = offs[n + 1];
    for (int i = s0; i < s1; ++i) {
        int eid = perm[i];
        int sn = (eid < E) ? src[eid] : (eid - E);
        float alpha = wE[(size_t)eid * 4 + head] * dinv;
        float2 hv = *(const float2*)(h1pre + (size_t)sn * 512 + f);
        ax += alpha * hv.x;
        ay += alpha * hv.y;
    }
    float vx = ax + b1[f], vy = ay + b1[f + 1];
    float2 o;
    o.x = ELU(vx);
    o.y = ELU(vy);
    *(float2*)(out1 + (size_t)n * 512 + f) = o;
}

// ---------------- layer-2 pieces (H=1, O=64) -------------------------------
__global__ __launch_bounds__(256) void al2_kernel(const float* __restrict__ h2pre,
                                                  const float* __restrict__ a_s,
                                                  const float* __restrict__ a_d,
                                                  float* __restrict__ alS,
                                                  float* __restrict__ alD, int Nn) {
    int n = blockIdx.x * 4 + (threadIdx.x >> 6);
    int lane = threadIdx.x & 63;
    if (n >= Nn) return;
    float v = h2pre[(size_t)n * 64 + lane];
    float s = v * a_s[lane];
    float d = v * a_d[lane];
#pragma unroll
    for (int off = 32; off; off >>= 1) {
        s += __shfl_down(s, off);
        d += __shfl_down(d, off);
    }
    if (lane == 0) { alS[n] = s; alD[n] = d; }
}

__global__ __launch_bounds__(256) void edgew2_kernel(const int* __restrict__ src,
                                                     const int* __restrict__ dst,
                                                     int E, int Nn,
                                                     const float* __restrict__ alS,
                                                     const float* __restrict__ alD,
                                                     float* __restrict__ wE) {
    int e = blockIdx.x * 256 + threadIdx.x;
    if (e >= E + Nn) return;
    int s = (e < E) ? src[e] : (e - E);
    int d = (e < E) ? dst[e] : (e - E);
    float t = alS[s] + alD[d];
    wE[e] = expf(LRELU(t));
}

__global__ __launch_bounds__(256) void denom2_kernel(const int* __restrict__ offs,
                                                     const int* __restrict__ perm,
                                                     const float* __restrict__ wE,
                                                     float* __restrict__ denom, int Nn) {
    int n = blockIdx.x * 256 + threadIdx.x;
    if (n >= Nn) return;
    int s0 = offs[n], s1 = offs[n + 1];
    float sum = 0.f;
    for (int i = s0; i < s1; ++i) sum += wE[perm[i]];
    denom[n] = sum;
}

__global__ __launch_bounds__(256) void agg2_kernel(const float* __restrict__ h2pre,
                                                   const int* __restrict__ src,
                                                   const int* __restrict__ offs,
                                                   const int* __restrict__ perm,
                                                   const float* __restrict__ wE,
                                                   const float* __restrict__ denom,
                                                   const float* __restrict__ b2,
                                                   float* __restrict__ out2,
                                                   int E, int Nn) {
    int n = blockIdx.x * 4 + (threadIdx.x >> 6);
    int f = threadIdx.x & 63;
    if (n >= Nn) return;
    float dinv = 1.0f / denom[n];
    float acc = 0.f;
    int s0 = offs[n], s1 = offs[n + 1];
    for (int i = s0; i < s1; ++i) {
        int eid = perm[i];
        int sn = (eid < E) ? src[eid] : (eid - E);
        float alpha = wE[eid] * dinv;
        acc += alpha * h2pre[(size_t)sn * 64 + f];
    }
    float v = acc + b2[f];
    out2[(size_t)n * 64 + f] = ELU(v);
}

// ---------------- pool + head ----------------------------------------------
__device__ __forceinline__ int lower_bound_i(const int* arr, int n, int key) {
    int lo = 0, hi = n;
    while (lo < hi) {
        int mid = (lo + hi) >> 1;
        if (arr[mid] < key) lo = mid + 1; else hi = mid;
    }
    return lo;
}

__global__ __launch_bounds__(64) void pool_kernel(const float* __restrict__ h2,
                                                  const int* __restrict__ batch,
                                                  int Nn, float* __restrict__ pooled) {
    int g = blockIdx.x;
    __shared__ int sh[2];
    if (threadIdx.x == 0) sh[0] = lower_bound_i(batch, Nn, g);
    if (threadIdx.x == 1) sh[1] = lower_bound_i(batch, Nn, g + 1);
    __syncthreads();
    int s0 = sh[0], s1 = sh[1];
    float sum = 0.f;
    for (int i = s0; i < s1; ++i) sum += h2[(size_t)i * 64 + threadIdx.x];
    float cnt = (float)((s1 - s0) > 1 ? (s1 - s0) : 1);
    pooled[(size_t)g * 64 + threadIdx.x] = sum / cnt;
}

__global__ __launch_bounds__(64) void fc_kernel(const float* __restrict__ pooled,
                                                const float* __restrict__ w1,
                                                const float* __restrict__ bb1,
                                                const float* __restrict__ w2,
                                                const float* __restrict__ bb2,
                                                float* __restrict__ out) {
    int g = blockIdx.x;
    __shared__ float p[64];
    __shared__ float hid[32];
    int t = threadIdx.x;
    p[t] = pooled[(size_t)g * 64 + t];
    __syncthreads();
    if (t < 32) {
        float a = bb1[t];
#pragma unroll
        for (int k = 0; k < 64; ++k) a += p[k] * w1[k * 32 + t];
        hid[t] = a > 0.f ? a : 0.f;
    }
    __syncthreads();
    if (t == 0) {
        float a = bb2[0];
#pragma unroll
        for (int j = 0; j < 32; ++j) a += hid[j] * w2[j];
        out[g] = 1.0f / (1.0f + expf(-a));
    }
}

// ---------------------------------------------------------------------------
extern "C" void kernel_launch(void* const* d_in, const int* in_sizes, int n_in,
                              void* d_out, int out_size, void* d_ws, size_t ws_size,
                              hipStream_t stream) {
    const float* x      = (const float*)d_in[0];
    const int*   ei     = (const int*)d_in[1];
    const int*   batch  = (const int*)d_in[2];
    const float* W1     = (const float*)d_in[3];
    const float* a_src1 = (const float*)d_in[4];
    const float* a_dst1 = (const float*)d_in[5];
    const float* b1     = (const float*)d_in[6];
    const float* W2     = (const float*)d_in[7];
    const float* a_src2 = (const float*)d_in[8];
    const float* a_dst2 = (const float*)d_in[9];
    const float* b2     = (const float*)d_in[10];
    const float* fcw1   = (const float*)d_in[11];
    const float* fcb1   = (const float*)d_in[12];
    const float* fcw2   = (const float*)d_in[13];
    const float* fcb2   = (const float*)d_in[14];
    float* out = (float*)d_out;

    const int Nn = in_sizes[0] / 128;   // 25000
    const int E  = in_sizes[1] / 2;     // 400000
    const int Et = E + Nn;              // with self loops
    const int NG = out_size;            // 512
    const int* srcA = ei;
    const int* dstA = ei + E;

    // workspace carve-up (256B aligned)
    char* base = (char*)d_ws;
    size_t off = 0;
    auto alloc = [&](size_t bytes) -> void* {
        void* p = base + off;
        off += (bytes + 255) & ~(size_t)255;
        return p;
    };
    float* h1pre  = (float*)alloc((size_t)Nn * 512 * 4);   // also reused as h2pre
    float* out1   = (float*)alloc((size_t)Nn * 512 * 4);   // also reused as out2
    float* alS1   = (float*)alloc((size_t)Nn * 4 * 4);
    float* alD1   = (float*)alloc((size_t)Nn * 4 * 4);
    float* alS2   = (float*)alloc((size_t)Nn * 4);
    float* alD2   = (float*)alloc((size_t)Nn * 4);
    float* wE1    = (float*)alloc((size_t)Et * 4 * 4);
    float* wE2    = (float*)alloc((size_t)Et * 4);
    float* denom1 = (float*)alloc((size_t)Nn * 4 * 4);
    float* denom2 = (float*)alloc((size_t)Nn * 4);
    int*   deg    = (int*)alloc((size_t)2 * Nn * 4);       // deg + fill contiguous
    int*   fill   = deg + Nn;
    int*   offs   = (int*)alloc((size_t)(Nn + 1) * 4);
    int*   perm   = (int*)alloc((size_t)Et * 4);
    float* pooled = (float*)alloc((size_t)NG * 64 * 4);
    float* h2pre  = h1pre;   // alias: h1pre dead after agg1
    float* out2   = out1;    // alias: out1 dead after gemm2
    (void)ws_size; (void)n_in;

    const int EB = (Et + 255) / 256;

    // ---- layer 1 ----
    dim3 g1((Nn + 63) / 64, 512 / 64);
    gemm_f32<<<g1, 256, 0, stream>>>(x, W1, h1pre, Nn, 512, 128);
    al1_kernel<<<Nn, 256, 0, stream>>>(h1pre, a_src1, a_dst1, alS1, alD1, Nn);

    hipMemsetAsync(deg, 0, sizeof(int) * 2 * Nn, stream);
    count_kernel<<<EB, 256, 0, stream>>>(dstA, E, Nn, deg);
    scan_kernel<<<1, 1024, 0, stream>>>(deg, offs, Nn);
    scatter_kernel<<<EB, 256, 0, stream>>>(dstA, E, Nn, offs, fill, perm);

    edgew1_kernel<<<EB, 256, 0, stream>>>(srcA, dstA, E, Nn, alS1, alD1, wE1);
    denom1_kernel<<<(Nn * 4 + 255) / 256, 256, 0, stream>>>(offs, perm, wE1, denom1, Nn);
    agg1_kernel<<<Nn, 256, 0, stream>>>(h1pre, srcA, offs, perm, wE1, denom1, b1, out1, E, Nn);

    // ---- layer 2 ----
    dim3 g2((Nn + 63) / 64, 1);
    gemm_f32<<<g2, 256, 0, stream>>>(out1, W2, h2pre, Nn, 64, 512);
    al2_kernel<<<(Nn + 3) / 4, 256, 0, stream>>>(h2pre, a_src2, a_dst2, alS2, alD2, Nn);
    edgew2_kernel<<<EB, 256, 0, stream>>>(srcA, dstA, E, Nn, alS2, alD2, wE2);
    denom2_kernel<<<(Nn + 255) / 256, 256, 0, stream>>>(offs, perm, wE2, denom2, Nn);
    agg2_kernel<<<(Nn + 3) / 4, 256, 0, stream>>>(h2pre, srcA, offs, perm, wE2, denom2, b2, out2, E, Nn);

    // ---- pool + head ----
    pool_kernel<<<NG, 64, 0, stream>>>(out2, batch, Nn, pooled);
    fc_kernel<<<NG, 64, 0, stream>>>(pooled, fcw1, fcb1, fcw2, fcb2, out);
}

// Round 2
// 392.000 us; speedup vs baseline: 1.3137x; 1.3137x over previous
//
#include <hip/hip_runtime.h>
#include <hip/hip_bf16.h>

// ---------------------------------------------------------------------------
// GAT (2 layers) + mean pool + MLP head, fp32.
// Key restructure vs R0: layer-1 aggregation moved BEFORE the GEMM via
// associativity  elu((A_hat @ x) @ W1 + b1)  ==  elu(A_hat @ (x @ W1) + b1),
// so the per-edge gather reads 512B x-rows (12.8 MB, L2-resident) instead of
// 2KB h1pre rows (51 MB, HBM). Attention logits come from the folded
// Wa = [W1 . a_src | W1 . a_dst]  ([128,8]) so h1pre is never materialized.
// Softmax (exp/sum/div) is fused into the aggregate kernels.
// ---------------------------------------------------------------------------

#define LRELU(v) ((v) > 0.0f ? (v) : 0.2f * (v))
#define ELU(v)   ((v) > 0.0f ? (v) : expm1f(v))

// ---- fold W1 with a_src/a_dst: Wa[k][j] ; j<4 -> src head j, j>=4 -> dst ---
__global__ __launch_bounds__(256) void wa_kernel(const float* __restrict__ W1,
                                                 const float* __restrict__ a_s,
                                                 const float* __restrict__ a_d,
                                                 float* __restrict__ Wa) {
    int idx = blockIdx.x * 256 + threadIdx.x;   // 0..1023
    int k = idx >> 3, j = idx & 7, h = j & 3;
    const float* a = (j < 4) ? (a_s + h * 128) : (a_d + h * 128);
    const float* wrow = W1 + (size_t)k * 512 + h * 128;
    float s = 0.f;
#pragma unroll 8
    for (int o = 0; o < 128; ++o) s += wrow[o] * a[o];
    Wa[k * 8 + j] = s;
}

// ---- alS1/alD1 = x @ Wa  (one wave per node) ------------------------------
__global__ __launch_bounds__(256) void al12_kernel(const float* __restrict__ x,
                                                   const float* __restrict__ Wa,
                                                   float* __restrict__ alS,
                                                   float* __restrict__ alD, int Nn) {
    int lane = threadIdx.x & 63;
    int wave = threadIdx.x >> 6;
    float4 ls = *(const float4*)(Wa + lane * 8);
    float4 ld = *(const float4*)(Wa + lane * 8 + 4);
    float4 hs = *(const float4*)(Wa + (lane + 64) * 8);
    float4 hd = *(const float4*)(Wa + (lane + 64) * 8 + 4);
    int n = blockIdx.x * 4 + wave;
    if (n >= Nn) return;
    float x0 = x[(size_t)n * 128 + lane];
    float x1 = x[(size_t)n * 128 + lane + 64];
    float r0 = x0 * ls.x + x1 * hs.x;
    float r1 = x0 * ls.y + x1 * hs.y;
    float r2 = x0 * ls.z + x1 * hs.z;
    float r3 = x0 * ls.w + x1 * hs.w;
    float r4 = x0 * ld.x + x1 * hd.x;
    float r5 = x0 * ld.y + x1 * hd.y;
    float r6 = x0 * ld.z + x1 * hd.z;
    float r7 = x0 * ld.w + x1 * hd.w;
#pragma unroll
    for (int off = 32; off; off >>= 1) {
        r0 += __shfl_down(r0, off); r1 += __shfl_down(r1, off);
        r2 += __shfl_down(r2, off); r3 += __shfl_down(r3, off);
        r4 += __shfl_down(r4, off); r5 += __shfl_down(r5, off);
        r6 += __shfl_down(r6, off); r7 += __shfl_down(r7, off);
    }
    if (lane == 0) {
        *(float4*)(alS + (size_t)n * 4) = make_float4(r0, r1, r2, r3);
        *(float4*)(alD + (size_t)n * 4) = make_float4(r4, r5, r6, r7);
    }
}

// ---------------- CSR build ------------------------------------------------
__global__ __launch_bounds__(256) void count_kernel(const int* __restrict__ dst,
                                                    int E, int Nn, int* __restrict__ deg) {
    int e = blockIdx.x * 256 + threadIdx.x;
    if (e >= E + Nn) return;
    int d = (e < E) ? dst[e] : (e - E);
    atomicAdd(&deg[d], 1);
}

__global__ __launch_bounds__(1024) void scan_kernel(const int* __restrict__ deg,
                                                    int* __restrict__ offs, int n) {
    __shared__ int sh[1024];
    int tid = threadIdx.x;
    int carry = 0;
    if (tid == 0) offs[0] = 0;
    for (int base = 0; base < n; base += 1024) {
        int i = base + tid;
        int v = (i < n) ? deg[i] : 0;
        sh[tid] = v;
        __syncthreads();
        for (int off = 1; off < 1024; off <<= 1) {
            int t = (tid >= off) ? sh[tid - off] : 0;
            __syncthreads();
            sh[tid] += t;
            __syncthreads();
        }
        if (i < n) offs[i + 1] = carry + sh[tid];
        int total = sh[1023];
        __syncthreads();
        carry += total;
    }
}

__global__ __launch_bounds__(256) void scatter_kernel(const int* __restrict__ dst,
                                                      int E, int Nn,
                                                      const int* __restrict__ offs,
                                                      int* __restrict__ fill,
                                                      int* __restrict__ perm) {
    int e = blockIdx.x * 256 + threadIdx.x;
    if (e >= E + Nn) return;
    int d = (e < E) ? dst[e] : (e - E);
    int pos = offs[d] + atomicAdd(&fill[d], 1);
    perm[pos] = e;
}

// ---- layer-1 fused softmax + aggregate of x: xagg[n, h*128+f] -------------
__global__ __launch_bounds__(64) void aggx_kernel(const float* __restrict__ x,
                                                  const int* __restrict__ src,
                                                  const int* __restrict__ offs,
                                                  const int* __restrict__ perm,
                                                  const float* __restrict__ alS,
                                                  const float* __restrict__ alD,
                                                  float* __restrict__ xagg,
                                                  int E, int Nn) {
    int n = blockIdx.x;
    int t = threadIdx.x;               // 0..63, 2 feats per lane
    float4 ad = *(const float4*)(alD + (size_t)n * 4);
    float a0x = 0.f, a0y = 0.f, a1x = 0.f, a1y = 0.f;
    float a2x = 0.f, a2y = 0.f, a3x = 0.f, a3y = 0.f;
    float ws0 = 0.f, ws1 = 0.f, ws2 = 0.f, ws3 = 0.f;
    int s0 = offs[n], s1 = offs[n + 1];
    for (int i = s0; i < s1; ++i) {
        int eid = perm[i];
        int sn = (eid < E) ? src[eid] : (eid - E);
        float4 as = *(const float4*)(alS + (size_t)sn * 4);
        float t0 = as.x + ad.x; float w0 = expf(LRELU(t0));
        float t1 = as.y + ad.y; float w1 = expf(LRELU(t1));
        float t2 = as.z + ad.z; float w2 = expf(LRELU(t2));
        float t3 = as.w + ad.w; float w3 = expf(LRELU(t3));
        float2 xv = *(const float2*)(x + (size_t)sn * 128 + t * 2);
        a0x += w0 * xv.x; a0y += w0 * xv.y;
        a1x += w1 * xv.x; a1y += w1 * xv.y;
        a2x += w2 * xv.x; a2y += w2 * xv.y;
        a3x += w3 * xv.x; a3y += w3 * xv.y;
        ws0 += w0; ws1 += w1; ws2 += w2; ws3 += w3;
    }
    float* o = xagg + (size_t)n * 512 + t * 2;
    float i0 = 1.f / ws0, i1 = 1.f / ws1, i2 = 1.f / ws2, i3 = 1.f / ws3;
    *(float2*)(o + 0)   = make_float2(a0x * i0, a0y * i0);
    *(float2*)(o + 128) = make_float2(a1x * i1, a1y * i1);
    *(float2*)(o + 256) = make_float2(a2x * i2, a2y * i2);
    *(float2*)(o + 384) = make_float2(a3x * i3, a3y * i3);
}

// ---- out1 = elu(xagg_head @ W1[:,colblk] + b1) ; per-head panel GEMM ------
__global__ __launch_bounds__(256) void gemm_gat1(const float* __restrict__ xagg,
                                                 const float* __restrict__ W1,
                                                 const float* __restrict__ b1,
                                                 float* __restrict__ out1, int M) {
    __shared__ float As[16][64];
    __shared__ float Bs[16][64];
    int tid = threadIdx.x;
    int row0 = blockIdx.x * 64, col0 = blockIdx.y * 64;
    int head = blockIdx.y >> 1;            // 2 col-blocks per head
    const float* A = xagg + head * 128;    // lda = 512
    int tx = tid & 15, ty = tid >> 4;
    int la_r = tid >> 2, la_k = (tid & 3) * 4;
    int lb_k = tid >> 4, lb_c = (tid & 15) * 4;
    float acc[4][4] = {};
    for (int k0 = 0; k0 < 128; k0 += 16) {
        int ar = row0 + la_r;
        float4 av = make_float4(0.f, 0.f, 0.f, 0.f);
        if (ar < M) av = *(const float4*)(A + (size_t)ar * 512 + k0 + la_k);
        As[la_k + 0][la_r] = av.x;
        As[la_k + 1][la_r] = av.y;
        As[la_k + 2][la_r] = av.z;
        As[la_k + 3][la_r] = av.w;
        *(float4*)(&Bs[lb_k][lb_c]) =
            *(const float4*)(W1 + (size_t)(k0 + lb_k) * 512 + col0 + lb_c);
        __syncthreads();
#pragma unroll
        for (int kk = 0; kk < 16; ++kk) {
            float a[4], b[4];
#pragma unroll
            for (int i = 0; i < 4; ++i) a[i] = As[kk][ty * 4 + i];
#pragma unroll
            for (int j = 0; j < 4; ++j) b[j] = Bs[kk][tx * 4 + j];
#pragma unroll
            for (int i = 0; i < 4; ++i)
#pragma unroll
                for (int j = 0; j < 4; ++j) acc[i][j] += a[i] * b[j];
        }
        __syncthreads();
    }
    float4 bias = *(const float4*)(b1 + col0 + tx * 4);
#pragma unroll
    for (int i = 0; i < 4; ++i) {
        int r = row0 + ty * 4 + i;
        if (r < M) {
            float v0 = acc[i][0] + bias.x, v1 = acc[i][1] + bias.y;
            float v2 = acc[i][2] + bias.z, v3 = acc[i][3] + bias.w;
            float4 v = make_float4(ELU(v0), ELU(v1), ELU(v2), ELU(v3));
            *(float4*)(out1 + (size_t)r * 512 + col0 + tx * 4) = v;
        }
    }
}

// ---- generic fp32 GEMM (layer 2): C = A @ B --------------------------------
__global__ __launch_bounds__(256) void gemm_f32(const float* __restrict__ A,
                                                const float* __restrict__ B,
                                                float* __restrict__ C,
                                                int M, int N, int K) {
    __shared__ float As[16][64];
    __shared__ float Bs[16][64];
    int tid = threadIdx.x;
    int row0 = blockIdx.x * 64, col0 = blockIdx.y * 64;
    int tx = tid & 15, ty = tid >> 4;
    int la_r = tid >> 2, la_k = (tid & 3) * 4;
    int lb_k = tid >> 4, lb_c = (tid & 15) * 4;
    float acc[4][4] = {};
    for (int k0 = 0; k0 < K; k0 += 16) {
        int ar = row0 + la_r;
        float4 av = make_float4(0.f, 0.f, 0.f, 0.f);
        if (ar < M) av = *(const float4*)(A + (size_t)ar * K + k0 + la_k);
        As[la_k + 0][la_r] = av.x;
        As[la_k + 1][la_r] = av.y;
        As[la_k + 2][la_r] = av.z;
        As[la_k + 3][la_r] = av.w;
        *(float4*)(&Bs[lb_k][lb_c]) =
            *(const float4*)(B + (size_t)(k0 + lb_k) * N + col0 + lb_c);
        __syncthreads();
#pragma unroll
        for (int kk = 0; kk < 16; ++kk) {
            float a[4], b[4];
#pragma unroll
            for (int i = 0; i < 4; ++i) a[i] = As[kk][ty * 4 + i];
#pragma unroll
            for (int j = 0; j < 4; ++j) b[j] = Bs[kk][tx * 4 + j];
#pragma unroll
            for (int i = 0; i < 4; ++i)
#pragma unroll
                for (int j = 0; j < 4; ++j) acc[i][j] += a[i] * b[j];
        }
        __syncthreads();
    }
#pragma unroll
    for (int i = 0; i < 4; ++i) {
        int r = row0 + ty * 4 + i;
        if (r < M) {
            float4 v = make_float4(acc[i][0], acc[i][1], acc[i][2], acc[i][3]);
            *(float4*)(C + (size_t)r * N + col0 + tx * 4) = v;
        }
    }
}

// ---------------- layer-2 logits (H=1, O=64) -------------------------------
__global__ __launch_bounds__(256) void al2_kernel(const float* __restrict__ h2pre,
                                                  const float* __restrict__ a_s,
                                                  const float* __restrict__ a_d,
                                                  float* __restrict__ alS,
                                                  float* __restrict__ alD, int Nn) {
    int n = blockIdx.x * 4 + (threadIdx.x >> 6);
    int lane = threadIdx.x & 63;
    if (n >= Nn) return;
    float v = h2pre[(size_t)n * 64 + lane];
    float s = v * a_s[lane];
    float d = v * a_d[lane];
#pragma unroll
    for (int off = 32; off; off >>= 1) {
        s += __shfl_down(s, off);
        d += __shfl_down(d, off);
    }
    if (lane == 0) { alS[n] = s; alD[n] = d; }
}

// ---- layer-2 fused softmax + aggregate + bias + ELU -----------------------
__global__ __launch_bounds__(256) void agg2_kernel(const float* __restrict__ h2pre,
                                                   const int* __restrict__ src,
                                                   const int* __restrict__ offs,
                                                   const int* __restrict__ perm,
                                                   const float* __restrict__ alS,
                                                   const float* __restrict__ alD,
                                                   const float* __restrict__ b2,
                                                   float* __restrict__ out2,
                                                   int E, int Nn) {
    int n = blockIdx.x * 4 + (threadIdx.x >> 6);
    int f = threadIdx.x & 63;
    if (n >= Nn) return;
    float ad = alD[n];
    float acc = 0.f, wsum = 0.f;
    int s0 = offs[n], s1 = offs[n + 1];
    for (int i = s0; i < s1; ++i) {
        int eid = perm[i];
        int sn = (eid < E) ? src[eid] : (eid - E);
        float t = alS[sn] + ad;
        float w = expf(LRELU(t));
        wsum += w;
        acc += w * h2pre[(size_t)sn * 64 + f];
    }
    float v = acc / wsum + b2[f];
    out2[(size_t)n * 64 + f] = ELU(v);
}

// ---------------- pool + head ----------------------------------------------
__device__ __forceinline__ int lower_bound_i(const int* arr, int n, int key) {
    int lo = 0, hi = n;
    while (lo < hi) {
        int mid = (lo + hi) >> 1;
        if (arr[mid] < key) lo = mid + 1; else hi = mid;
    }
    return lo;
}

__global__ __launch_bounds__(64) void pool_kernel(const float* __restrict__ h2,
                                                  const int* __restrict__ batch,
                                                  int Nn, float* __restrict__ pooled) {
    int g = blockIdx.x;
    __shared__ int sh[2];
    if (threadIdx.x == 0) sh[0] = lower_bound_i(batch, Nn, g);
    if (threadIdx.x == 1) sh[1] = lower_bound_i(batch, Nn, g + 1);
    __syncthreads();
    int s0 = sh[0], s1 = sh[1];
    float sum = 0.f;
    for (int i = s0; i < s1; ++i) sum += h2[(size_t)i * 64 + threadIdx.x];
    float cnt = (float)((s1 - s0) > 1 ? (s1 - s0) : 1);
    pooled[(size_t)g * 64 + threadIdx.x] = sum / cnt;
}

__global__ __launch_bounds__(64) void fc_kernel(const float* __restrict__ pooled,
                                                const float* __restrict__ w1,
                                                const float* __restrict__ bb1,
                                                const float* __restrict__ w2,
                                                const float* __restrict__ bb2,
                                                float* __restrict__ out) {
    int g = blockIdx.x;
    __shared__ float p[64];
    __shared__ float hid[32];
    int t = threadIdx.x;
    p[t] = pooled[(size_t)g * 64 + t];
    __syncthreads();
    if (t < 32) {
        float a = bb1[t];
#pragma unroll
        for (int k = 0; k < 64; ++k) a += p[k] * w1[k * 32 + t];
        hid[t] = a > 0.f ? a : 0.f;
    }
    __syncthreads();
    if (t == 0) {
        float a = bb2[0];
#pragma unroll
        for (int j = 0; j < 32; ++j) a += hid[j] * w2[j];
        out[g] = 1.0f / (1.0f + expf(-a));
    }
}

// ---------------------------------------------------------------------------
extern "C" void kernel_launch(void* const* d_in, const int* in_sizes, int n_in,
                              void* d_out, int out_size, void* d_ws, size_t ws_size,
                              hipStream_t stream) {
    const float* x      = (const float*)d_in[0];
    const int*   ei     = (const int*)d_in[1];
    const int*   batch  = (const int*)d_in[2];
    const float* W1     = (const float*)d_in[3];
    const float* a_src1 = (const float*)d_in[4];
    const float* a_dst1 = (const float*)d_in[5];
    const float* b1     = (const float*)d_in[6];
    const float* W2     = (const float*)d_in[7];
    const float* a_src2 = (const float*)d_in[8];
    const float* a_dst2 = (const float*)d_in[9];
    const float* b2     = (const float*)d_in[10];
    const float* fcw1   = (const float*)d_in[11];
    const float* fcb1   = (const float*)d_in[12];
    const float* fcw2   = (const float*)d_in[13];
    const float* fcb2   = (const float*)d_in[14];
    float* out = (float*)d_out;

    const int Nn = in_sizes[0] / 128;   // 25000
    const int E  = in_sizes[1] / 2;     // 400000
    const int Et = E + Nn;
    const int NG = out_size;            // 512
    const int* srcA = ei;
    const int* dstA = ei + E;

    char* base = (char*)d_ws;
    size_t off = 0;
    auto alloc = [&](size_t bytes) -> void* {
        void* p = base + off;
        off += (bytes + 255) & ~(size_t)255;
        return p;
    };
    float* xagg   = (float*)alloc((size_t)Nn * 512 * 4);   // reused as h2pre
    float* out1   = (float*)alloc((size_t)Nn * 512 * 4);   // reused as out2
    float* Wa     = (float*)alloc(128 * 8 * 4);
    float* alS1   = (float*)alloc((size_t)Nn * 4 * 4);
    float* alD1   = (float*)alloc((size_t)Nn * 4 * 4);
    float* alS2   = (float*)alloc((size_t)Nn * 4);
    float* alD2   = (float*)alloc((size_t)Nn * 4);
    int*   deg    = (int*)alloc((size_t)2 * Nn * 4);       // deg + fill
    int*   fill   = deg + Nn;
    int*   offs   = (int*)alloc((size_t)(Nn + 1) * 4);
    int*   perm   = (int*)alloc((size_t)Et * 4);
    float* pooled = (float*)alloc((size_t)NG * 64 * 4);
    float* h2pre  = xagg;   // xagg dead after gemm_gat1
    float* out2   = out1;   // out1 dead after gemm2
    (void)ws_size; (void)n_in;

    const int EB = (Et + 255) / 256;

    // ---- layer 1 ----
    wa_kernel<<<4, 256, 0, stream>>>(W1, a_src1, a_dst1, Wa);
    al12_kernel<<<(Nn + 3) / 4, 256, 0, stream>>>(x, Wa, alS1, alD1, Nn);

    hipMemsetAsync(deg, 0, sizeof(int) * 2 * Nn, stream);
    count_kernel<<<EB, 256, 0, stream>>>(dstA, E, Nn, deg);
    scan_kernel<<<1, 1024, 0, stream>>>(deg, offs, Nn);
    scatter_kernel<<<EB, 256, 0, stream>>>(dstA, E, Nn, offs, fill, perm);

    aggx_kernel<<<Nn, 64, 0, stream>>>(x, srcA, offs, perm, alS1, alD1, xagg, E, Nn);
    dim3 g1((Nn + 63) / 64, 8);
    gemm_gat1<<<g1, 256, 0, stream>>>(xagg, W1, b1, out1, Nn);

    // ---- layer 2 ----
    dim3 g2((Nn + 63) / 64, 1);
    gemm_f32<<<g2, 256, 0, stream>>>(out1, W2, h2pre, Nn, 64, 512);
    al2_kernel<<<(Nn + 3) / 4, 256, 0, stream>>>(h2pre, a_src2, a_dst2, alS2, alD2, Nn);
    agg2_kernel<<<(Nn + 3) / 4, 256, 0, stream>>>(h2pre, srcA, offs, perm, alS2, alD2,
                                                  b2, out2, E, Nn);

    // ---- pool + head ----
    pool_kernel<<<NG, 64, 0, stream>>>(out2, batch, Nn, pooled);
    fc_kernel<<<NG, 64, 0, stream>>>(pooled, fcw1, fcb1, fcw2, fcb2, out);
}

// Round 3
// 353.933 us; speedup vs baseline: 1.4550x; 1.1076x over previous
//
#include <hip/hip_runtime.h>
#include <hip/hip_bf16.h>

// ---------------------------------------------------------------------------
// GAT (2 layers) + mean pool + MLP head, fp32.
// R1->R2: per-edge exp weights computed ONCE per edge (edgew kernels) instead
// of redundantly in all 64 lanes of the aggregate kernels (R1 aggx was
// VALU-bound at 72% from 109M redundant expf). Hierarchical 3-phase scan
// replaces the single-block scan. Layer-1 GEMM upgraded to 128x128 tile,
// 8x8 microtile.
// ---------------------------------------------------------------------------

#define LRELU(v) ((v) > 0.0f ? (v) : 0.2f * (v))
#define ELU(v)   ((v) > 0.0f ? (v) : expm1f(v))

// ---- fold W1 with a_src/a_dst: Wa[k][j] ; j<4 -> src head j, j>=4 -> dst ---
__global__ __launch_bounds__(256) void wa_kernel(const float* __restrict__ W1,
                                                 const float* __restrict__ a_s,
                                                 const float* __restrict__ a_d,
                                                 float* __restrict__ Wa) {
    int idx = blockIdx.x * 256 + threadIdx.x;   // 0..1023
    int k = idx >> 3, j = idx & 7, h = j & 3;
    const float* a = (j < 4) ? (a_s + h * 128) : (a_d + h * 128);
    const float* wrow = W1 + (size_t)k * 512 + h * 128;
    float s = 0.f;
#pragma unroll 8
    for (int o = 0; o < 128; ++o) s += wrow[o] * a[o];
    Wa[k * 8 + j] = s;
}

// ---- alS1/alD1 = x @ Wa  (one wave per node) ------------------------------
__global__ __launch_bounds__(256) void al12_kernel(const float* __restrict__ x,
                                                   const float* __restrict__ Wa,
                                                   float* __restrict__ alS,
                                                   float* __restrict__ alD, int Nn) {
    int lane = threadIdx.x & 63;
    int wave = threadIdx.x >> 6;
    float4 ls = *(const float4*)(Wa + lane * 8);
    float4 ld = *(const float4*)(Wa + lane * 8 + 4);
    float4 hs = *(const float4*)(Wa + (lane + 64) * 8);
    float4 hd = *(const float4*)(Wa + (lane + 64) * 8 + 4);
    int n = blockIdx.x * 4 + wave;
    if (n >= Nn) return;
    float x0 = x[(size_t)n * 128 + lane];
    float x1 = x[(size_t)n * 128 + lane + 64];
    float r0 = x0 * ls.x + x1 * hs.x;
    float r1 = x0 * ls.y + x1 * hs.y;
    float r2 = x0 * ls.z + x1 * hs.z;
    float r3 = x0 * ls.w + x1 * hs.w;
    float r4 = x0 * ld.x + x1 * hd.x;
    float r5 = x0 * ld.y + x1 * hd.y;
    float r6 = x0 * ld.z + x1 * hd.z;
    float r7 = x0 * ld.w + x1 * hd.w;
#pragma unroll
    for (int off = 32; off; off >>= 1) {
        r0 += __shfl_down(r0, off); r1 += __shfl_down(r1, off);
        r2 += __shfl_down(r2, off); r3 += __shfl_down(r3, off);
        r4 += __shfl_down(r4, off); r5 += __shfl_down(r5, off);
        r6 += __shfl_down(r6, off); r7 += __shfl_down(r7, off);
    }
    if (lane == 0) {
        *(float4*)(alS + (size_t)n * 4) = make_float4(r0, r1, r2, r3);
        *(float4*)(alD + (size_t)n * 4) = make_float4(r4, r5, r6, r7);
    }
}

// ---------------- CSR build ------------------------------------------------
__global__ __launch_bounds__(256) void count_kernel(const int* __restrict__ dst,
                                                    int E, int Nn, int* __restrict__ deg) {
    int e = blockIdx.x * 256 + threadIdx.x;
    if (e >= E + Nn) return;
    int d = (e < E) ? dst[e] : (e - E);
    atomicAdd(&deg[d], 1);
}

// 3-phase scan: A) per-block (2048 elems) inclusive scan + block totals
__global__ __launch_bounds__(256) void scanA_kernel(const int* __restrict__ deg,
                                                    int* __restrict__ offs,
                                                    int* __restrict__ bsum, int n) {
    __shared__ int sh[256];
    int b = blockIdx.x, t = threadIdx.x;
    int base = b * 2048 + t * 8;
    int v[8]; int s = 0;
#pragma unroll
    for (int j = 0; j < 8; ++j) { int i = base + j; v[j] = (i < n) ? deg[i] : 0; s += v[j]; }
    sh[t] = s;
    __syncthreads();
    for (int off = 1; off < 256; off <<= 1) {
        int u = (t >= off) ? sh[t - off] : 0;
        __syncthreads();
        sh[t] += u;
        __syncthreads();
    }
    int run = sh[t] - s;                 // exclusive prefix of this thread's chunk
    if (t == 255) bsum[b] = sh[255];
#pragma unroll
    for (int j = 0; j < 8; ++j) {
        run += v[j];
        int i = base + j;
        if (i < n) offs[i + 1] = run;
    }
}

// B) single-wave scan of block totals (nb <= 64)
__global__ __launch_bounds__(64) void scanB_kernel(int* __restrict__ bsum, int nb) {
    int t = threadIdx.x;
    int v = (t < nb) ? bsum[t] : 0;
#pragma unroll
    for (int off = 1; off < 64; off <<= 1) {
        int u = __shfl_up(v, off);
        if (t >= off) v += u;
    }
    if (t < nb) bsum[t] = v;
}

// C) add scanned block totals
__global__ __launch_bounds__(256) void scanC_kernel(int* __restrict__ offs,
                                                    const int* __restrict__ bsum, int n) {
    int i = blockIdx.x * 256 + threadIdx.x;
    if (i == 0) offs[0] = 0;
    if (i >= n) return;
    int b = i >> 11;
    if (b > 0) offs[i + 1] += bsum[b - 1];
}

__global__ __launch_bounds__(256) void scatter_kernel(const int* __restrict__ dst,
                                                      int E, int Nn,
                                                      const int* __restrict__ offs,
                                                      int* __restrict__ fill,
                                                      int* __restrict__ perm) {
    int e = blockIdx.x * 256 + threadIdx.x;
    if (e >= E + Nn) return;
    int d = (e < E) ? dst[e] : (e - E);
    int pos = offs[d] + atomicAdd(&fill[d], 1);
    perm[pos] = e;
}

// ---- per-edge exp(leaky(.)) weights, layer 1 (H=4) ------------------------
__global__ __launch_bounds__(256) void edgew1_kernel(const int* __restrict__ src,
                                                     const int* __restrict__ dst,
                                                     int E, int Nn,
                                                     const float* __restrict__ alS,
                                                     const float* __restrict__ alD,
                                                     float* __restrict__ wE) {
    int e = blockIdx.x * 256 + threadIdx.x;
    if (e >= E + Nn) return;
    int s = (e < E) ? src[e] : (e - E);
    int d = (e < E) ? dst[e] : (e - E);
    float4 as = *(const float4*)(alS + (size_t)s * 4);
    float4 ad = *(const float4*)(alD + (size_t)d * 4);
    float4 w;
    float t;
    t = as.x + ad.x; w.x = expf(LRELU(t));
    t = as.y + ad.y; w.y = expf(LRELU(t));
    t = as.z + ad.z; w.z = expf(LRELU(t));
    t = as.w + ad.w; w.w = expf(LRELU(t));
    *(float4*)(wE + (size_t)e * 4) = w;
}

// ---- layer-1 fused aggregate of x (weights precomputed) -------------------
__global__ __launch_bounds__(64) void aggx_kernel(const float* __restrict__ x,
                                                  const int* __restrict__ src,
                                                  const int* __restrict__ offs,
                                                  const int* __restrict__ perm,
                                                  const float* __restrict__ wE,
                                                  float* __restrict__ xagg,
                                                  int E) {
    int n = blockIdx.x;
    int t = threadIdx.x;               // 0..63, 2 feats per lane
    float a0x = 0.f, a0y = 0.f, a1x = 0.f, a1y = 0.f;
    float a2x = 0.f, a2y = 0.f, a3x = 0.f, a3y = 0.f;
    float ws0 = 0.f, ws1 = 0.f, ws2 = 0.f, ws3 = 0.f;
    int s0 = offs[n], s1 = offs[n + 1];
    for (int i = s0; i < s1; ++i) {
        int eid = perm[i];
        int sn = (eid < E) ? src[eid] : (eid - E);
        float4 w = *(const float4*)(wE + (size_t)eid * 4);   // wave-broadcast
        float2 xv = *(const float2*)(x + (size_t)sn * 128 + t * 2);
        a0x += w.x * xv.x; a0y += w.x * xv.y;
        a1x += w.y * xv.x; a1y += w.y * xv.y;
        a2x += w.z * xv.x; a2y += w.z * xv.y;
        a3x += w.w * xv.x; a3y += w.w * xv.y;
        ws0 += w.x; ws1 += w.y; ws2 += w.z; ws3 += w.w;
    }
    float* o = xagg + (size_t)n * 512 + t * 2;
    float i0 = 1.f / ws0, i1 = 1.f / ws1, i2 = 1.f / ws2, i3 = 1.f / ws3;
    *(float2*)(o + 0)   = make_float2(a0x * i0, a0y * i0);
    *(float2*)(o + 128) = make_float2(a1x * i1, a1y * i1);
    *(float2*)(o + 256) = make_float2(a2x * i2, a2y * i2);
    *(float2*)(o + 384) = make_float2(a3x * i3, a3y * i3);
}

// ---- out1 = elu(xagg_head @ W1_panel + b1): 128x128 tile, 8x8 micro -------
__global__ __launch_bounds__(256) void gemm_gat1(const float* __restrict__ xagg,
                                                 const float* __restrict__ W1,
                                                 const float* __restrict__ b1,
                                                 float* __restrict__ out1, int M) {
    __shared__ __attribute__((aligned(16))) float As[16][128];
    __shared__ __attribute__((aligned(16))) float Bs[16][128];
    int tid = threadIdx.x;
    int row0 = blockIdx.x * 128;
    int head = blockIdx.y;
    int col0 = head * 128;
    const float* A = xagg + col0;        // head panel, lda = 512
    int tx = tid & 15, ty = tid >> 4;

    int la_r = tid >> 1;                 // 0..127
    int la_k = (tid & 1) * 8;            // 0 or 8
    int lb_k = tid >> 4;                 // 0..15
    int lb_c = (tid & 15) * 8;           // 0..120

    float acc[8][8] = {};

    for (int k0 = 0; k0 < 128; k0 += 16) {
        int ar = row0 + la_r;
        float4 av0 = make_float4(0.f, 0.f, 0.f, 0.f), av1 = av0;
        if (ar < M) {
            const float* ap = A + (size_t)ar * 512 + k0 + la_k;
            av0 = *(const float4*)(ap);
            av1 = *(const float4*)(ap + 4);
        }
        As[la_k + 0][la_r] = av0.x; As[la_k + 1][la_r] = av0.y;
        As[la_k + 2][la_r] = av0.z; As[la_k + 3][la_r] = av0.w;
        As[la_k + 4][la_r] = av1.x; As[la_k + 5][la_r] = av1.y;
        As[la_k + 6][la_r] = av1.z; As[la_k + 7][la_r] = av1.w;
        const float* bp = W1 + (size_t)(k0 + lb_k) * 512 + col0 + lb_c;
        *(float4*)(&Bs[lb_k][lb_c])     = *(const float4*)(bp);
        *(float4*)(&Bs[lb_k][lb_c + 4]) = *(const float4*)(bp + 4);
        __syncthreads();
#pragma unroll
        for (int kk = 0; kk < 16; ++kk) {
            float a[8], b[8];
            *(float4*)&a[0] = *(const float4*)&As[kk][ty * 8];
            *(float4*)&a[4] = *(const float4*)&As[kk][ty * 8 + 4];
            *(float4*)&b[0] = *(const float4*)&Bs[kk][tx * 8];
            *(float4*)&b[4] = *(const float4*)&Bs[kk][tx * 8 + 4];
#pragma unroll
            for (int i = 0; i < 8; ++i)
#pragma unroll
                for (int j = 0; j < 8; ++j) acc[i][j] += a[i] * b[j];
        }
        __syncthreads();
    }
    float bias[8];
    *(float4*)&bias[0] = *(const float4*)(b1 + col0 + tx * 8);
    *(float4*)&bias[4] = *(const float4*)(b1 + col0 + tx * 8 + 4);
#pragma unroll
    for (int i = 0; i < 8; ++i) {
        int r = row0 + ty * 8 + i;
        if (r < M) {
            float v[8];
#pragma unroll
            for (int j = 0; j < 8; ++j) { float u = acc[i][j] + bias[j]; v[j] = ELU(u); }
            float* cp = out1 + (size_t)r * 512 + col0 + tx * 8;
            *(float4*)(cp)     = *(float4*)&v[0];
            *(float4*)(cp + 4) = *(float4*)&v[4];
        }
    }
}

// ---- generic fp32 GEMM (layer 2): C = A @ B --------------------------------
__global__ __launch_bounds__(256) void gemm_f32(const float* __restrict__ A,
                                                const float* __restrict__ B,
                                                float* __restrict__ C,
                                                int M, int N, int K) {
    __shared__ __attribute__((aligned(16))) float As[16][64];
    __shared__ __attribute__((aligned(16))) float Bs[16][64];
    int tid = threadIdx.x;
    int row0 = blockIdx.x * 64, col0 = blockIdx.y * 64;
    int tx = tid & 15, ty = tid >> 4;
    int la_r = tid >> 2, la_k = (tid & 3) * 4;
    int lb_k = tid >> 4, lb_c = (tid & 15) * 4;
    float acc[4][4] = {};
    for (int k0 = 0; k0 < K; k0 += 16) {
        int ar = row0 + la_r;
        float4 av = make_float4(0.f, 0.f, 0.f, 0.f);
        if (ar < M) av = *(const float4*)(A + (size_t)ar * K + k0 + la_k);
        As[la_k + 0][la_r] = av.x;
        As[la_k + 1][la_r] = av.y;
        As[la_k + 2][la_r] = av.z;
        As[la_k + 3][la_r] = av.w;
        *(float4*)(&Bs[lb_k][lb_c]) =
            *(const float4*)(B + (size_t)(k0 + lb_k) * N + col0 + lb_c);
        __syncthreads();
#pragma unroll
        for (int kk = 0; kk < 16; ++kk) {
            float a[4], b[4];
#pragma unroll
            for (int i = 0; i < 4; ++i) a[i] = As[kk][ty * 4 + i];
#pragma unroll
            for (int j = 0; j < 4; ++j) b[j] = Bs[kk][tx * 4 + j];
#pragma unroll
            for (int i = 0; i < 4; ++i)
#pragma unroll
                for (int j = 0; j < 4; ++j) acc[i][j] += a[i] * b[j];
        }
        __syncthreads();
    }
#pragma unroll
    for (int i = 0; i < 4; ++i) {
        int r = row0 + ty * 4 + i;
        if (r < M) {
            float4 v = make_float4(acc[i][0], acc[i][1], acc[i][2], acc[i][3]);
            *(float4*)(C + (size_t)r * N + col0 + tx * 4) = v;
        }
    }
}

// ---------------- layer-2 logits (H=1, O=64) -------------------------------
__global__ __launch_bounds__(256) void al2_kernel(const float* __restrict__ h2pre,
                                                  const float* __restrict__ a_s,
                                                  const float* __restrict__ a_d,
                                                  float* __restrict__ alS,
                                                  float* __restrict__ alD, int Nn) {
    int n = blockIdx.x * 4 + (threadIdx.x >> 6);
    int lane = threadIdx.x & 63;
    if (n >= Nn) return;
    float v = h2pre[(size_t)n * 64 + lane];
    float s = v * a_s[lane];
    float d = v * a_d[lane];
#pragma unroll
    for (int off = 32; off; off >>= 1) {
        s += __shfl_down(s, off);
        d += __shfl_down(d, off);
    }
    if (lane == 0) { alS[n] = s; alD[n] = d; }
}

__global__ __launch_bounds__(256) void edgew2_kernel(const int* __restrict__ src,
                                                     const int* __restrict__ dst,
                                                     int E, int Nn,
                                                     const float* __restrict__ alS,
                                                     const float* __restrict__ alD,
                                                     float* __restrict__ wE) {
    int e = blockIdx.x * 256 + threadIdx.x;
    if (e >= E + Nn) return;
    int s = (e < E) ? src[e] : (e - E);
    int d = (e < E) ? dst[e] : (e - E);
    float t = alS[s] + alD[d];
    wE[e] = expf(LRELU(t));
}

// ---- layer-2 aggregate (weights precomputed) + bias + ELU -----------------
__global__ __launch_bounds__(256) void agg2_kernel(const float* __restrict__ h2pre,
                                                   const int* __restrict__ src,
                                                   const int* __restrict__ offs,
                                                   const int* __restrict__ perm,
                                                   const float* __restrict__ wE,
                                                   const float* __restrict__ b2,
                                                   float* __restrict__ out2,
                                                   int E, int Nn) {
    int n = blockIdx.x * 4 + (threadIdx.x >> 6);
    int f = threadIdx.x & 63;
    if (n >= Nn) return;
    float acc = 0.f, wsum = 0.f;
    int s0 = offs[n], s1 = offs[n + 1];
    for (int i = s0; i < s1; ++i) {
        int eid = perm[i];
        int sn = (eid < E) ? src[eid] : (eid - E);
        float w = wE[eid];
        wsum += w;
        acc += w * h2pre[(size_t)sn * 64 + f];
    }
    float v = acc / wsum + b2[f];
    out2[(size_t)n * 64 + f] = ELU(v);
}

// ---------------- pool + head ----------------------------------------------
__device__ __forceinline__ int lower_bound_i(const int* arr, int n, int key) {
    int lo = 0, hi = n;
    while (lo < hi) {
        int mid = (lo + hi) >> 1;
        if (arr[mid] < key) lo = mid + 1; else hi = mid;
    }
    return lo;
}

__global__ __launch_bounds__(64) void pool_kernel(const float* __restrict__ h2,
                                                  const int* __restrict__ batch,
                                                  int Nn, float* __restrict__ pooled) {
    int g = blockIdx.x;
    __shared__ int sh[2];
    if (threadIdx.x == 0) sh[0] = lower_bound_i(batch, Nn, g);
    if (threadIdx.x == 1) sh[1] = lower_bound_i(batch, Nn, g + 1);
    __syncthreads();
    int s0 = sh[0], s1 = sh[1];
    float sum = 0.f;
    for (int i = s0; i < s1; ++i) sum += h2[(size_t)i * 64 + threadIdx.x];
    float cnt = (float)((s1 - s0) > 1 ? (s1 - s0) : 1);
    pooled[(size_t)g * 64 + threadIdx.x] = sum / cnt;
}

__global__ __launch_bounds__(64) void fc_kernel(const float* __restrict__ pooled,
                                                const float* __restrict__ w1,
                                                const float* __restrict__ bb1,
                                                const float* __restrict__ w2,
                                                const float* __restrict__ bb2,
                                                float* __restrict__ out) {
    int g = blockIdx.x;
    __shared__ float p[64];
    __shared__ float hid[32];
    int t = threadIdx.x;
    p[t] = pooled[(size_t)g * 64 + t];
    __syncthreads();
    if (t < 32) {
        float a = bb1[t];
#pragma unroll
        for (int k = 0; k < 64; ++k) a += p[k] * w1[k * 32 + t];
        hid[t] = a > 0.f ? a : 0.f;
    }
    __syncthreads();
    if (t == 0) {
        float a = bb2[0];
#pragma unroll
        for (int j = 0; j < 32; ++j) a += hid[j] * w2[j];
        out[g] = 1.0f / (1.0f + expf(-a));
    }
}

// ---------------------------------------------------------------------------
extern "C" void kernel_launch(void* const* d_in, const int* in_sizes, int n_in,
                              void* d_out, int out_size, void* d_ws, size_t ws_size,
                              hipStream_t stream) {
    const float* x      = (const float*)d_in[0];
    const int*   ei     = (const int*)d_in[1];
    const int*   batch  = (const int*)d_in[2];
    const float* W1     = (const float*)d_in[3];
    const float* a_src1 = (const float*)d_in[4];
    const float* a_dst1 = (const float*)d_in[5];
    const float* b1     = (const float*)d_in[6];
    const float* W2     = (const float*)d_in[7];
    const float* a_src2 = (const float*)d_in[8];
    const float* a_dst2 = (const float*)d_in[9];
    const float* b2     = (const float*)d_in[10];
    const float* fcw1   = (const float*)d_in[11];
    const float* fcb1   = (const float*)d_in[12];
    const float* fcw2   = (const float*)d_in[13];
    const float* fcb2   = (const float*)d_in[14];
    float* out = (float*)d_out;

    const int Nn = in_sizes[0] / 128;   // 25000
    const int E  = in_sizes[1] / 2;     // 400000
    const int Et = E + Nn;
    const int NG = out_size;            // 512
    const int* srcA = ei;
    const int* dstA = ei + E;

    char* base = (char*)d_ws;
    size_t off = 0;
    auto alloc = [&](size_t bytes) -> void* {
        void* p = base + off;
        off += (bytes + 255) & ~(size_t)255;
        return p;
    };
    float* xagg   = (float*)alloc((size_t)Nn * 512 * 4);   // reused as h2pre
    float* out1   = (float*)alloc((size_t)Nn * 512 * 4);   // reused as out2
    float* Wa     = (float*)alloc(128 * 8 * 4);
    float* alS1   = (float*)alloc((size_t)Nn * 4 * 4);
    float* alD1   = (float*)alloc((size_t)Nn * 4 * 4);
    float* alS2   = (float*)alloc((size_t)Nn * 4);
    float* alD2   = (float*)alloc((size_t)Nn * 4);
    float* wE1    = (float*)alloc((size_t)Et * 4 * 4);
    float* wE2    = (float*)alloc((size_t)Et * 4);
    int*   deg    = (int*)alloc((size_t)2 * Nn * 4);       // deg + fill
    int*   fill   = deg + Nn;
    int*   offs   = (int*)alloc((size_t)(Nn + 1) * 4);
    int*   bsum   = (int*)alloc(64 * 4);
    int*   perm   = (int*)alloc((size_t)Et * 4);
    float* pooled = (float*)alloc((size_t)NG * 64 * 4);
    float* h2pre  = xagg;   // xagg dead after gemm_gat1
    float* out2   = out1;   // out1 dead after gemm2
    (void)ws_size; (void)n_in;

    const int EB = (Et + 255) / 256;
    const int NB = (Nn + 2047) / 2048;   // scan blocks

    // ---- CSR build + layer-1 logits ----
    wa_kernel<<<4, 256, 0, stream>>>(W1, a_src1, a_dst1, Wa);
    al12_kernel<<<(Nn + 3) / 4, 256, 0, stream>>>(x, Wa, alS1, alD1, Nn);

    hipMemsetAsync(deg, 0, sizeof(int) * 2 * Nn, stream);
    count_kernel<<<EB, 256, 0, stream>>>(dstA, E, Nn, deg);
    scanA_kernel<<<NB, 256, 0, stream>>>(deg, offs, bsum, Nn);
    scanB_kernel<<<1, 64, 0, stream>>>(bsum, NB);
    scanC_kernel<<<(Nn + 255) / 256, 256, 0, stream>>>(offs, bsum, Nn);
    scatter_kernel<<<EB, 256, 0, stream>>>(dstA, E, Nn, offs, fill, perm);

    // ---- layer 1 ----
    edgew1_kernel<<<EB, 256, 0, stream>>>(srcA, dstA, E, Nn, alS1, alD1, wE1);
    aggx_kernel<<<Nn, 64, 0, stream>>>(x, srcA, offs, perm, wE1, xagg, E);
    dim3 g1((Nn + 127) / 128, 4);
    gemm_gat1<<<g1, 256, 0, stream>>>(xagg, W1, b1, out1, Nn);

    // ---- layer 2 ----
    dim3 g2((Nn + 63) / 64, 1);
    gemm_f32<<<g2, 256, 0, stream>>>(out1, W2, h2pre, Nn, 64, 512);
    al2_kernel<<<(Nn + 3) / 4, 256, 0, stream>>>(h2pre, a_src2, a_dst2, alS2, alD2, Nn);
    edgew2_kernel<<<EB, 256, 0, stream>>>(srcA, dstA, E, Nn, alS2, alD2, wE2);
    agg2_kernel<<<(Nn + 3) / 4, 256, 0, stream>>>(h2pre, srcA, offs, perm, wE2,
                                                  b2, out2, E, Nn);

    // ---- pool + head ----
    pool_kernel<<<NG, 64, 0, stream>>>(out2, batch, Nn, pooled);
    fc_kernel<<<NG, 64, 0, stream>>>(pooled, fcw1, fcb1, fcw2, fcb2, out);
}